// Round 12
// baseline (414.053 us; speedup 1.0000x reference)
//
#include <hip/hip_runtime.h>

#define NF    25     // input features per row
#define NPAIR 300    // upper-triangle pairs (25*24/2)
#define NCOL  425    // output cols: 25*5 + 300
#define ROWS  8      // rows per chunk
#define BLK   256
#define TILE4N 850                    // float4s per chunk (13600 B)
#define NP_TOT (ROWS * NPAIR)         // 2400 pair products per chunk
#define KFULL  (NP_TOT / BLK)         // 9 full passes
#define KREM   (NP_TOT - KFULL * BLK) // 96 tail threads

typedef float f32x4 __attribute__((ext_vector_type(4)));
typedef unsigned int u32;

// One chunk per block, no grid-stride loop: cross-chunk overlap is delegated
// to the HW scheduler (block churn), not a software pipeline. Body = round 9.
__global__ __launch_bounds__(BLK) void feat_expand_kernel(
    const float* __restrict__ x, float* __restrict__ out, int nrows) {
  __shared__ f32x4 tile4[TILE4N];           // 13600 B
  __shared__ float xs[ROWS * NF];           // 800 B
  float* tile = (float*)tile4;

  const int tid = threadIdx.x;
  const int r200 = tid / NF, i200 = tid - r200 * NF;

  // Static B2 descriptors (decode once; overlapped by other blocks' memory)
  u32 ab[KFULL + 1];
  u32 ti[KFULL + 1];
#pragma unroll
  for (int k = 0; k <= KFULL; ++k) {
    int p = tid + k * BLK;
    if (p >= NP_TOT) p = 0;                 // dummy; predicated off at use
    const int r = p / NPAIR;
    const int q = p - r * NPAIR;
    int rem = q, i = 0;
    while (rem >= (NF - 1 - i)) { rem -= (NF - 1 - i); ++i; }
    ab[k] = (u32)(r * NF + i) | ((u32)(r * NF + i + 1 + rem) << 16);
    ti[k] = (u32)(r * NCOL + 5 * NF + q);
  }

  const long long chunk = blockIdx.x;
  const long long rowbase = chunk * ROWS;
  const long long remr = nrows - rowbase;
  const int rows_here = (int)(remr < ROWS ? remr : ROWS);

  // Phase A: load own element, publish to xs
  float v = 0.0f;
  if (tid < ROWS * NF) {
    if (r200 < rows_here) v = x[rowbase * NF + tid];
    xs[tid] = v;
  }
  __syncthreads();

  // Phase B1: unary features from the register
  if (tid < ROWS * NF) {
    float* tr = &tile[r200 * NCOL];
    const float ax = fabsf(v) + 1e-10f;
    const float l2 = __builtin_amdgcn_logf(ax);          // v_log_f32: log2
    tr[i200]        = v;                                 // identity
    tr[NF + i200]   = v * v;                             // square
    tr[2*NF + i200] = l2 * 0.69314718055994530942f;      // ln = log2*ln2
    tr[3*NF + i200] = sqrtf(ax);                         // v_sqrt_f32
    tr[4*NF + i200] = __builtin_amdgcn_exp2f(l2 * (1.0f/3.0f)); // cbrt
  }

  // Phase B2: pair products (static descriptors, zero decode)
#pragma unroll
  for (int k = 0; k <= KFULL; ++k) {
    if (k < KFULL || tid < KREM) {
      const u32 d = ab[k];
      tile[ti[k]] = xs[d & 0xFFFF] * xs[d >> 16];
    }
  }
  __syncthreads();

  // Phase C: aligned float4 nt-stores (850 = 3*256 + 82)
  if (rows_here == ROWS) {
    f32x4* __restrict__ o4 = (f32x4*)(out + rowbase * NCOL);
#pragma unroll
    for (int k = 0; k < 4; ++k) {
      const int v4 = tid + k * BLK;
      if (k < 3 || v4 < TILE4N)
        __builtin_nontemporal_store(tile4[v4], &o4[v4]);
    }
  } else {  // tail chunk (not hit when nrows % ROWS == 0)
    const int total = rows_here * NCOL;
    for (int o = tid; o < total; o += BLK)
      out[rowbase * NCOL + o] = tile[o];
  }
}

extern "C" void kernel_launch(void* const* d_in, const int* in_sizes, int n_in,
                              void* d_out, int out_size, void* d_ws, size_t ws_size,
                              hipStream_t stream) {
  const float* x = (const float*)d_in[0];
  float* out = (float*)d_out;

  const int nrows = in_sizes[0] / NF;                 // 524288
  const int nchunks = (nrows + ROWS - 1) / ROWS;      // 65536 blocks
  feat_expand_kernel<<<nchunks, BLK, 0, stream>>>(x, out, nrows);
}

// Round 13
// 192.668 us; speedup vs baseline: 2.1490x; 2.1490x over previous
//
#include <hip/hip_runtime.h>

#define NF    25     // input features per row
#define NPAIR 300    // upper-triangle pairs (25*24/2)
#define NCOL  425    // output cols: 25*5 + 300
#define ROWS  16     // rows per chunk (was 8 — the one never-varied axis)
#define BLK   256
#define LOADN  (ROWS * NF)            // 400 staged x per chunk
#define TILE4N (ROWS * NCOL / 4)      // 1700 float4s (27200 B)
#define NP_TOT (ROWS * NPAIR)         // 4800 pair products per chunk
#define KFULL  (NP_TOT / BLK)         // 18 full passes
#define KREM   (NP_TOT - KFULL * BLK) // 192 tail threads
#define C4FULL (TILE4N / BLK)         // 6 full store passes
#define C4REM  (TILE4N - C4FULL * BLK)// 164 tail

typedef float f32x4 __attribute__((ext_vector_type(4)));
typedef unsigned int u32;

__global__ __launch_bounds__(BLK) void feat_expand_kernel(
    const float* __restrict__ x, float* __restrict__ out,
    int nrows, int nchunks) {
  __shared__ f32x4 tile4[TILE4N];           // 27200 B
  __shared__ float xs[LOADN];               // 1600 B
  float* tile = (float*)tile4;

  const int tid = threadIdx.x;

  // Hoisted static B2 descriptors (chunk-independent) — R9 technique
  u32 ab[KFULL + 1];
  u32 ti[KFULL + 1];
#pragma unroll
  for (int k = 0; k <= KFULL; ++k) {
    int p = tid + k * BLK;
    if (p >= NP_TOT) p = 0;                 // dummy; predicated off at use
    const int r = p / NPAIR;
    const int q = p - r * NPAIR;
    int rem = q, i = 0;
    while (rem >= (NF - 1 - i)) { rem -= (NF - 1 - i); ++i; }
    ab[k] = (u32)(r * NF + i) | ((u32)(r * NF + i + 1 + rem) << 16);
    ti[k] = (u32)(r * NCOL + 5 * NF + q);
  }

  for (long long chunk = blockIdx.x; chunk < nchunks; chunk += gridDim.x) {
    const long long rowbase = chunk * ROWS;
    const long long remr = nrows - rowbase;
    const int rows_here = (int)(remr < ROWS ? remr : ROWS);

    __syncthreads();  // prev C readers of tile / xs done

    // Phase A: stage 400 x values (2 coalesced passes), keep own 2 in regs
    float va[2];
#pragma unroll
    for (int k = 0; k < 2; ++k) {
      const int idx = tid + k * BLK;        // 400 = 2*256 - 112
      if (idx < LOADN) {
        const int r = idx / NF;
        float v = 0.0f;
        if (r < rows_here) v = x[rowbase * NF + idx];
        xs[idx] = v;
        va[k] = v;
      }
    }
    __syncthreads();  // xs ready

    // Phase B1: unary features from own registers (no xs re-read)
#pragma unroll
    for (int k = 0; k < 2; ++k) {
      const int idx = tid + k * BLK;
      if (idx < LOADN) {
        const int r = idx / NF, i = idx - r * NF;
        float* tr = &tile[r * NCOL];
        const float v  = va[k];
        const float ax = fabsf(v) + 1e-10f;
        const float l2 = __builtin_amdgcn_logf(ax);      // v_log_f32: log2
        tr[i]          = v;                              // identity
        tr[NF + i]     = v * v;                          // square
        tr[2*NF + i]   = l2 * 0.69314718055994530942f;   // ln = log2*ln2
        tr[3*NF + i]   = sqrtf(ax);                      // v_sqrt_f32
        tr[4*NF + i]   = __builtin_amdgcn_exp2f(l2 * (1.0f/3.0f)); // cbrt
      }
    }

    // Phase B2: pair products — static descriptors, zero decode
#pragma unroll
    for (int k = 0; k <= KFULL; ++k) {
      if (k < KFULL || tid < KREM) {
        const u32 d = ab[k];
        tile[ti[k]] = xs[d & 0xFFFF] * xs[d >> 16];
      }
    }
    __syncthreads();  // tile ready

    // Phase C: 27.2 KB contiguous nt float4 burst (1700 = 6*256 + 164)
    if (rows_here == ROWS) {
      f32x4* __restrict__ o4 = (f32x4*)(out + rowbase * NCOL);
#pragma unroll
      for (int k = 0; k <= C4FULL; ++k) {
        const int v4 = tid + k * BLK;
        if (k < C4FULL || tid < C4REM)
          __builtin_nontemporal_store(tile4[v4], &o4[v4]);
      }
    } else {  // tail chunk (not hit when nrows % ROWS == 0)
      const int total = rows_here * NCOL;
      for (int o = tid; o < total; o += BLK)
        out[rowbase * NCOL + o] = tile[o];
    }
  }
}

extern "C" void kernel_launch(void* const* d_in, const int* in_sizes, int n_in,
                              void* d_out, int out_size, void* d_ws, size_t ws_size,
                              hipStream_t stream) {
  const float* x = (const float*)d_in[0];
  float* out = (float*)d_out;

  const int nrows = in_sizes[0] / NF;                 // 524288
  const int nchunks = (nrows + ROWS - 1) / ROWS;      // 32768
  const int grid = nchunks < 4096 ? nchunks : 4096;

  feat_expand_kernel<<<grid, BLK, 0, stream>>>(x, out, nrows, nchunks);
}

// Round 14
// 190.326 us; speedup vs baseline: 2.1755x; 1.0123x over previous
//
#include <hip/hip_runtime.h>

#define NF    25     // input features per row
#define NPAIR 300    // upper-triangle pairs (25*24/2)
#define NCOL  425    // output cols: 25*5 + 300
#define ROWS  32     // rows per chunk (R13 axis, doubled again)
#define BLK   512    // scales with ROWS: per-thread trip counts match R13
#define LOADN  (ROWS * NF)            // 800 staged x per chunk
#define TILE4N (ROWS * NCOL / 4)      // 3400 float4s (54400 B)
#define NP_TOT (ROWS * NPAIR)         // 9600 pair products per chunk
#define KFULL  (NP_TOT / BLK)         // 18 full passes
#define KREM   (NP_TOT - KFULL * BLK) // 384 tail threads
#define C4FULL (TILE4N / BLK)         // 6 full store passes
#define C4REM  (TILE4N - C4FULL * BLK)// 328 tail

typedef float f32x4 __attribute__((ext_vector_type(4)));
typedef unsigned int u32;

__global__ __launch_bounds__(BLK, 4) void feat_expand_kernel(
    const float* __restrict__ x, float* __restrict__ out,
    int nrows, int nchunks) {
  __shared__ f32x4 tile4[TILE4N];           // 54400 B
  __shared__ float xs[LOADN];               // 3200 B  -> 57.6 KB, 2 blocks/CU
  float* tile = (float*)tile4;

  const int tid = threadIdx.x;

  // Hoisted static B2 descriptors (chunk-independent) — R9 technique
  u32 ab[KFULL + 1];
  u32 ti[KFULL + 1];
#pragma unroll
  for (int k = 0; k <= KFULL; ++k) {
    int p = tid + k * BLK;
    if (p >= NP_TOT) p = 0;                 // dummy; predicated off at use
    const int r = p / NPAIR;
    const int q = p - r * NPAIR;
    int rem = q, i = 0;
    while (rem >= (NF - 1 - i)) { rem -= (NF - 1 - i); ++i; }
    ab[k] = (u32)(r * NF + i) | ((u32)(r * NF + i + 1 + rem) << 16);
    ti[k] = (u32)(r * NCOL + 5 * NF + q);
  }

  for (long long chunk = blockIdx.x; chunk < nchunks; chunk += gridDim.x) {
    const long long rowbase = chunk * ROWS;
    const long long remr = nrows - rowbase;
    const int rows_here = (int)(remr < ROWS ? remr : ROWS);

    __syncthreads();  // prev C readers of tile / xs done

    // Phase A: stage 800 x values (2 coalesced passes), keep own 2 in regs
    float va[2];
#pragma unroll
    for (int k = 0; k < 2; ++k) {
      const int idx = tid + k * BLK;        // 800 = 2*512 - 224
      if (idx < LOADN) {
        const int r = idx / NF;
        float v = 0.0f;
        if (r < rows_here) v = x[rowbase * NF + idx];
        xs[idx] = v;
        va[k] = v;
      }
    }
    __syncthreads();  // xs ready

    // Phase B1: unary features from own registers (no xs re-read)
#pragma unroll
    for (int k = 0; k < 2; ++k) {
      const int idx = tid + k * BLK;
      if (idx < LOADN) {
        const int r = idx / NF, i = idx - r * NF;
        float* tr = &tile[r * NCOL];
        const float v  = va[k];
        const float ax = fabsf(v) + 1e-10f;
        const float l2 = __builtin_amdgcn_logf(ax);      // v_log_f32: log2
        tr[i]          = v;                              // identity
        tr[NF + i]     = v * v;                          // square
        tr[2*NF + i]   = l2 * 0.69314718055994530942f;   // ln = log2*ln2
        tr[3*NF + i]   = sqrtf(ax);                      // v_sqrt_f32
        tr[4*NF + i]   = __builtin_amdgcn_exp2f(l2 * (1.0f/3.0f)); // cbrt
      }
    }

    // Phase B2: pair products — static descriptors, zero decode
#pragma unroll
    for (int k = 0; k <= KFULL; ++k) {
      if (k < KFULL || tid < KREM) {
        const u32 d = ab[k];
        tile[ti[k]] = xs[d & 0xFFFF] * xs[d >> 16];
      }
    }
    __syncthreads();  // tile ready

    // Phase C: 54.4 KB contiguous nt float4 burst (3400 = 6*512 + 328)
    if (rows_here == ROWS) {
      f32x4* __restrict__ o4 = (f32x4*)(out + rowbase * NCOL);
#pragma unroll
      for (int k = 0; k <= C4FULL; ++k) {
        const int v4 = tid + k * BLK;
        if (k < C4FULL || tid < C4REM)
          __builtin_nontemporal_store(tile4[v4], &o4[v4]);
      }
    } else {  // tail chunk (not hit when nrows % ROWS == 0)
      const int total = rows_here * NCOL;
      for (int o = tid; o < total; o += BLK)
        out[rowbase * NCOL + o] = tile[o];
    }
  }
}

extern "C" void kernel_launch(void* const* d_in, const int* in_sizes, int n_in,
                              void* d_out, int out_size, void* d_ws, size_t ws_size,
                              hipStream_t stream) {
  const float* x = (const float*)d_in[0];
  float* out = (float*)d_out;

  const int nrows = in_sizes[0] / NF;                 // 524288
  const int nchunks = (nrows + ROWS - 1) / ROWS;      // 16384
  // Exact residency: 2 blocks/CU * 256 CU = 512; each block loops 32 chunks
  // with a warm pipeline and zero block churn (R12 showed churn is costly).
  const int grid = nchunks < 512 ? nchunks : 512;

  feat_expand_kernel<<<grid, BLK, 0, stream>>>(x, out, nrows, nchunks);
}